// Round 4
// baseline (1413.028 us; speedup 1.0000x reference)
//
#include <hip/hip_runtime.h>

typedef unsigned short u16;
typedef unsigned int u32;
typedef short bf16x8 __attribute__((ext_vector_type(8)));
typedef float f32x4 __attribute__((ext_vector_type(4)));

#define AS1 __attribute__((address_space(1)))
#define AS3 __attribute__((address_space(3)))

__device__ __forceinline__ u16 f2b(float f) {
  u32 u = __float_as_uint(f);
  u += 0x7fffu + ((u >> 16) & 1u);   // round-to-nearest-even
  return (u16)(u >> 16);
}
__device__ __forceinline__ float b2f(u16 s) {
  return __uint_as_float(((u32)s) << 16);
}

__device__ __forceinline__ void gload16(const u16* g, u16* l) {
  __builtin_amdgcn_global_load_lds((const AS1 void*)g, (AS3 void*)l, 16, 0, 0);
}

// ---------------- cast x (f32) -> bf16 ----------------
__global__ __launch_bounds__(256) void cast_kernel(const float* __restrict__ x,
                                                   u16* __restrict__ xb, int n4) {
  int i = blockIdx.x * 256 + threadIdx.x;
  if (i >= n4) return;
  float4 v = ((const float4*)x)[i];
  ushort4 u;
  u.x = f2b(v.x); u.y = f2b(v.y); u.z = f2b(v.z); u.w = f2b(v.w);
  ((ushort4*)xb)[i] = u;
}

// ---------------- fill cls rows (token 0, bf16 residual) ----------------
__global__ __launch_bounds__(256) void cls_kernel(const float* __restrict__ cls,
                                                  u16* __restrict__ hb) {
  int i = blockIdx.x * 256 + threadIdx.x;  // B*128 threads, 4 elems each
  int b = i >> 7;
  int e = (i & 127) << 2;
  float4 v = *(const float4*)(cls + e);
  long off = (long)b * (25 * 512) + e;
  ushort4 u;
  u.x = f2b(v.x); u.y = f2b(v.y); u.z = f2b(v.z); u.w = f2b(v.w);
  *(ushort4*)(hb + off) = u;
}

// ---------------- transpose+convert: dst[n][k] (bf16) = src[k][n] (f32) ------
__global__ __launch_bounds__(256) void convT_kernel(const float* __restrict__ src,
                                                    u16* __restrict__ dst,
                                                    int K, int N,
                                                    long src_gstride, long dst_gstride) {
  __shared__ float t[64][65];
  const int k0 = blockIdx.x * 64, n0 = blockIdx.y * 64;
  const float* s = src + (long)blockIdx.z * src_gstride;
  u16* d = dst + (long)blockIdx.z * dst_gstride;
  for (int i = threadIdx.x; i < 4096; i += 256) {
    int r = i >> 6, c = i & 63;
    t[r][c] = s[(long)(k0 + r) * N + n0 + c];
  }
  __syncthreads();
  for (int i = threadIdx.x; i < 4096; i += 256) {
    int r = i >> 6, c = i & 63;  // r = n-local, c = k-local
    d[(long)(n0 + r) * K + k0 + c] = f2b(t[c][r]);
  }
}

// ---- fused per-layer weight convert: Wq(25 groups) + Wk + Wv + Wo, 512x512 ----
__global__ __launch_bounds__(256) void convT4_kernel(
    const float* __restrict__ wq, const float* __restrict__ wk,
    const float* __restrict__ wv, const float* __restrict__ wo,
    u16* __restrict__ dq, u16* __restrict__ dk,
    u16* __restrict__ dv, u16* __restrict__ dwo) {
  __shared__ float t[64][65];
  const int z = blockIdx.z;
  const float* src;
  u16* dst;
  if (z < 25)      { src = wq + (long)z * 262144; dst = dq + (long)z * 262144; }
  else if (z == 25){ src = wk; dst = dk; }
  else if (z == 26){ src = wv; dst = dv; }
  else             { src = wo; dst = dwo; }
  const int k0 = blockIdx.x * 64, n0 = blockIdx.y * 64;
  for (int i = threadIdx.x; i < 4096; i += 256) {
    int r = i >> 6, c = i & 63;
    t[r][c] = src[(long)(k0 + r) * 512 + n0 + c];
  }
  __syncthreads();
  for (int i = threadIdx.x; i < 4096; i += 256) {
    int r = i >> 6, c = i & 63;
    dst[(long)(n0 + r) * 512 + k0 + c] = f2b(t[c][r]);
  }
}

// ---------------- GEMM core: C = A @ Wt^T + bias ----------------
// A: bf16 [M][K] rows at a_stride; Wt: bf16 [N][K] row-major (pre-transposed).
// 128x128 tile, 4 waves, BK=64. 2-phase double-buffered (T3-min): issue next
// tile's global_load_lds into buf^1 BEFORE computing buf; one __syncthreads()
// per K-step (its vmcnt(0)+lgkmcnt(0) drain is the pipeline wait).
// LDS layout per buffer: [row][k] u16, XOR-swizzled (chunk ^= row&7) applied
// on the GLOBAL source + on ds_read (both-sides rule #21).
__device__ __forceinline__ void gemm_core(u16* lds,
    const u16* Ag, long a_stride, const u16* Wg, const float* biasg,
    u16* Cg, long c_stride, int K, int m0, int n0) {
  u16* As0 = lds;
  u16* Bs0 = lds + 8192;
  u16* As1 = lds + 16384;
  u16* Bs1 = lds + 24576;

  const int tid = threadIdx.x;
  const int lane = tid & 63;
  const int wave = tid >> 6;
  const int wr = wave >> 1, wc = wave & 1;

  // staging: wave covers 32 rows (4 instrs x 8 rows); lane -> row lane>>3,
  // chunk lane&7; LDS dest = wave-uniform base + lane*16B (HW rule).
  const int schunk = lane & 7;
  const u16* ga[4];
  const u16* gb[4];
  int lo[4];
#pragma unroll
  for (int i = 0; i < 4; ++i) {
    const int r = wave * 32 + i * 8 + (lane >> 3);
    const int csw = (schunk ^ (r & 7)) << 3;
    ga[i] = Ag + (long)(m0 + r) * a_stride + csw;
    gb[i] = Wg + (long)(n0 + r) * K + csw;
    lo[i] = (wave * 32 + i * 8) * 64;
  }

  f32x4 acc[4][4];
#pragma unroll
  for (int m = 0; m < 4; ++m)
#pragma unroll
    for (int n = 0; n < 4; ++n) {
      acc[m][n][0] = 0.f; acc[m][n][1] = 0.f;
      acc[m][n][2] = 0.f; acc[m][n][3] = 0.f;
    }

  auto STAGE = [&](int k0, u16* A, u16* B) {
#pragma unroll
    for (int i = 0; i < 4; ++i) {
      gload16(ga[i] + k0, A + lo[i]);
      gload16(gb[i] + k0, B + lo[i]);
    }
  };
  auto COMPUTE = [&](const u16* A, const u16* B) {
#pragma unroll
    for (int kk = 0; kk < 64; kk += 32) {
      const int kb = kk + ((lane >> 4) << 3);
      bf16x8 af[4], bfr[4];
#pragma unroll
      for (int m = 0; m < 4; ++m) {
        const int R = (wr << 6) + (m << 4) + (lane & 15);
        af[m] = *(const bf16x8*)&A[((R << 6) + kb) ^ ((R & 7) << 3)];
      }
#pragma unroll
      for (int n = 0; n < 4; ++n) {
        const int Cc = (wc << 6) + (n << 4) + (lane & 15);
        bfr[n] = *(const bf16x8*)&B[((Cc << 6) + kb) ^ ((Cc & 7) << 3)];
      }
#pragma unroll
      for (int m = 0; m < 4; ++m)
#pragma unroll
        for (int n = 0; n < 4; ++n)
          acc[m][n] = __builtin_amdgcn_mfma_f32_16x16x32_bf16(af[m], bfr[n],
                                                              acc[m][n], 0, 0, 0);
    }
  };

  const int nt = K >> 6;
  STAGE(0, As0, Bs0);
  __syncthreads();                       // tile 0 resident (vmcnt0 drain)
  for (int t = 0; t < nt; ++t) {
    u16* cA = (t & 1) ? As1 : As0;
    u16* cB = (t & 1) ? Bs1 : Bs0;
    if (t + 1 < nt) {
      u16* nA = (t & 1) ? As0 : As1;
      u16* nB = (t & 1) ? Bs0 : Bs1;
      STAGE((t + 1) << 6, nA, nB);       // in flight during compute
    }
    COMPUTE(cA, cB);
    if (t + 1 < nt) __syncthreads();     // drains next tile's loads + WAR fence
  }

  // epilogue: C/D layout col=lane&15, row=(lane>>4)*4+j (HW-verified)
  const int lcol = lane & 15;
  const int lrow = (lane >> 4) << 2;
#pragma unroll
  for (int n = 0; n < 4; ++n) {
    const int col = n0 + (wc << 6) + (n << 4) + lcol;
    const float bv = biasg[col];
#pragma unroll
    for (int m = 0; m < 4; ++m) {
      const int row = m0 + (wr << 6) + (m << 4) + lrow;
#pragma unroll
      for (int j = 0; j < 4; ++j) {
        const float val = acc[m][n][j] + bv;
        Cg[(long)(row + j) * c_stride + col] = f2b(val);
      }
    }
  }
}

// plain grouped wrapper: grid (mtiles, ntiles, groups)
__global__ __launch_bounds__(256) void gemm_plain(
    const u16* __restrict__ Abase, long a_stride, long a_goff,
    const u16* __restrict__ Wbase, long w_gstride,
    const float* __restrict__ biasbase, long bias_gstride,
    u16* __restrict__ Cb, long c_stride, long c_goff, int K) {
  __shared__ u16 lds[4 * 8192];
  const int g = blockIdx.z;
  gemm_core(lds,
            Abase + (long)g * a_goff, a_stride,
            Wbase + (long)g * w_gstride,
            biasbase + (long)g * bias_gstride,
            Cb + (long)g * c_goff, c_stride, K,
            blockIdx.x * 128, blockIdx.y * 128);
}

// fused Q(25 groups)+K+V: 1D grid of 2400 blocks
__global__ __launch_bounds__(256) void gemm_qkv(
    const u16* __restrict__ hb,
    const u16* __restrict__ wqT, const u16* __restrict__ wkT, const u16* __restrict__ wvT,
    const float* __restrict__ bq, const float* __restrict__ bk, const float* __restrict__ bv,
    u16* __restrict__ qb, u16* __restrict__ kb, u16* __restrict__ vb) {
  __shared__ u16 lds[4 * 8192];
  const int bid = blockIdx.x;
  const u16* Ag; long a_str; const u16* Wg; const float* bg; u16* Cg; long c_str;
  int mt, nt;
  if (bid < 800) {           // Q: per-joint groups
    const int g = bid >> 5, rem = bid & 31;
    mt = rem >> 2; nt = rem & 3;
    Ag = hb + (long)g * 512; a_str = 12800;
    Wg = wqT + (long)g * 262144; bg = bq + (long)g * 512;
    Cg = qb + (long)g * 512; c_str = 12800;
  } else if (bid < 1600) {   // K
    const int rem = bid - 800;
    mt = rem >> 2; nt = rem & 3;
    Ag = hb; a_str = 512; Wg = wkT; bg = bk; Cg = kb; c_str = 512;
  } else {                   // V
    const int rem = bid - 1600;
    mt = rem >> 2; nt = rem & 3;
    Ag = hb; a_str = 512; Wg = wvT; bg = bv; Cg = vb; c_str = 512;
  }
  gemm_core(lds, Ag, a_str, Wg, bg, Cg, c_str, 512, mt * 128, nt * 128);
}

// ---------------- attention: wave per (batch, head) ----------------
// __launch_bounds__(256,4): cap VGPR at 128 -> 4 blocks/CU (was 256 VGPR, 2).
__global__ __launch_bounds__(256, 4) void attn_kernel(const u16* __restrict__ q,
                                                      u16* __restrict__ kio,
                                                      const u16* __restrict__ v) {
  __shared__ u16 ks_[25 * 256];
  __shared__ u16 vs_[25 * 256];
  const int tid = threadIdx.x;
  const int b = blockIdx.x >> 1;
  const int h0 = blockIdx.x & 1;      // head-group (4 heads)
  const long base = (long)b * 25 * 512;

  for (int i = tid; i < 800; i += 256) {
    const int j = i >> 5, c = i & 31;
    const long goff = base + (long)j * 512 + h0 * 256 + c * 8;
    ((uint4*)ks_)[i] = *(const uint4*)(kio + goff);
    ((uint4*)vs_)[i] = *(const uint4*)(v + goff);
  }
  __syncthreads();

  const int w = tid >> 6;
  const int lane = tid & 63;
  const int qi = lane >> 1;
  const int half = lane & 1;
  if (qi < 25) {
    const int h = h0 * 4 + w;
    const int dslice = w * 64 + half * 32;

    const u16* qrow = q + base + (long)qi * 512 + h * 64 + half * 32;
    float buf[32];
#pragma unroll
    for (int c = 0; c < 4; ++c) {
      uint4 t = *(const uint4*)(qrow + c * 8);
      const u32 tt[4] = {t.x, t.y, t.z, t.w};
#pragma unroll
      for (int e = 0; e < 4; ++e) {
        buf[c * 8 + 2 * e]     = b2f((u16)tt[e]);
        buf[c * 8 + 2 * e + 1] = b2f((u16)(tt[e] >> 16));
      }
    }

    float sc[25];
    float mx = -1e30f;
#pragma unroll
    for (int j = 0; j < 25; ++j) {
      float s = 0.f;
      const u16* kr = &ks_[j * 256 + dslice];
#pragma unroll
      for (int d = 0; d < 32; d += 2) {
        u32 t = *(const u32*)(kr + d);
        s += buf[d] * b2f((u16)t) + buf[d + 1] * b2f((u16)(t >> 16));
      }
      s += __shfl_xor(s, 1);
      s *= 0.125f;
      sc[j] = s;
      mx = fmaxf(mx, s);
    }
    float sum = 0.f;
#pragma unroll
    for (int j = 0; j < 25; ++j) {
      sc[j] = __expf(sc[j] - mx);
      sum += sc[j];
    }
    const float inv = 1.f / sum;

#pragma unroll
    for (int d = 0; d < 32; ++d) buf[d] = 0.f;
#pragma unroll
    for (int j = 0; j < 25; ++j) {
      const float wj = sc[j];
      const u16* vr = &vs_[j * 256 + dslice];
#pragma unroll
      for (int d = 0; d < 32; d += 2) {
        u32 t = *(const u32*)(vr + d);
        buf[d]     += wj * b2f((u16)t);
        buf[d + 1] += wj * b2f((u16)(t >> 16));
      }
    }

    u16* orow = kio + base + (long)qi * 512 + h * 64 + half * 32;
#pragma unroll
    for (int c = 0; c < 4; ++c) {
      uint4 t;
      u32 tt[4];
#pragma unroll
      for (int e = 0; e < 4; ++e)
        tt[e] = (u32)f2b(buf[c * 8 + 2 * e] * inv) |
                ((u32)f2b(buf[c * 8 + 2 * e + 1] * inv) << 16);
      t.x = tt[0]; t.y = tt[1]; t.z = tt[2]; t.w = tt[3];
      *(uint4*)(orow + c * 8) = t;
    }
  }
}

// ---------------- residual + LayerNorm (bf16 residual) ----------------
__global__ __launch_bounds__(256) void ln_kernel(u16* hb,
                                                 const u16* __restrict__ o,
                                                 const float* __restrict__ g,
                                                 const float* __restrict__ bta,
                                                 float* fout) {
  const int lane = threadIdx.x & 63;
  const int wave = threadIdx.x >> 6;
  const long row = (long)blockIdx.x * 4 + wave;
  u16* hr = hb + row * 512;
  const u16* orow = o + row * 512;
  const int base = lane << 3;
  uint4 hv4 = *(const uint4*)(hr + base);
  uint4 ov = *(const uint4*)(orow + base);
  const u32 ha[4] = {hv4.x, hv4.y, hv4.z, hv4.w};
  const u32 oa[4] = {ov.x, ov.y, ov.z, ov.w};
  float y[8];
#pragma unroll
  for (int e = 0; e < 4; ++e) {
    y[2 * e]     = b2f((u16)ha[e])         + b2f((u16)oa[e]);
    y[2 * e + 1] = b2f((u16)(ha[e] >> 16)) + b2f((u16)(oa[e] >> 16));
  }
  float s = 0.f, ss = 0.f;
#pragma unroll
  for (int i = 0; i < 8; ++i) { s += y[i]; ss += y[i] * y[i]; }
#pragma unroll
  for (int off = 32; off > 0; off >>= 1) {
    s += __shfl_down(s, off);
    ss += __shfl_down(ss, off);
  }
  s = __shfl(s, 0);
  ss = __shfl(ss, 0);
  const float mean = s * (1.f / 512.f);
  const float var = ss * (1.f / 512.f) - mean * mean;
  const float rinv = rsqrtf(var + 1e-5f);
  float4 g0 = *(const float4*)(g + base);
  float4 g1 = *(const float4*)(g + base + 4);
  float4 b0 = *(const float4*)(bta + base);
  float4 b1 = *(const float4*)(bta + base + 4);
  float r[8];
  r[0] = (y[0] - mean) * rinv * g0.x + b0.x;
  r[1] = (y[1] - mean) * rinv * g0.y + b0.y;
  r[2] = (y[2] - mean) * rinv * g0.z + b0.z;
  r[3] = (y[3] - mean) * rinv * g0.w + b0.w;
  r[4] = (y[4] - mean) * rinv * g1.x + b1.x;
  r[5] = (y[5] - mean) * rinv * g1.y + b1.y;
  r[6] = (y[6] - mean) * rinv * g1.z + b1.z;
  r[7] = (y[7] - mean) * rinv * g1.w + b1.w;
  uint4 hv;
  hv.x = (u32)f2b(r[0]) | ((u32)f2b(r[1]) << 16);
  hv.y = (u32)f2b(r[2]) | ((u32)f2b(r[3]) << 16);
  hv.z = (u32)f2b(r[4]) | ((u32)f2b(r[5]) << 16);
  hv.w = (u32)f2b(r[6]) | ((u32)f2b(r[7]) << 16);
  *(uint4*)(hr + base) = hv;
  if (fout) {
    float* fr = fout + row * 512 + base;
    float4 w0 = {r[0], r[1], r[2], r[3]};
    float4 w1 = {r[4], r[5], r[6], r[7]};
    *(float4*)(fr) = w0;
    *(float4*)(fr + 4) = w1;
  }
}

// ---------------- host launcher ----------------
// d_in: x, We, be, cls, Wk, bk, Wv, bv, Wq, bq, Wo, bo, ln_g, ln_b
// ws (100 MiB): hb@0, kb@25M(=xb alias), vb@50M, qb@75M
// d_out doubles as bf16 weight scratch during layers; final LN rewrites it.
extern "C" void kernel_launch(void* const* d_in, const int* in_sizes, int n_in,
                              void* d_out, int out_size, void* d_ws, size_t ws_size,
                              hipStream_t stream) {
  const float* x   = (const float*)d_in[0];
  const float* We  = (const float*)d_in[1];
  const float* be  = (const float*)d_in[2];
  const float* cls = (const float*)d_in[3];
  const float* Wk  = (const float*)d_in[4];
  const float* bk  = (const float*)d_in[5];
  const float* Wv  = (const float*)d_in[6];
  const float* bv  = (const float*)d_in[7];
  const float* Wq  = (const float*)d_in[8];
  const float* bq  = (const float*)d_in[9];
  const float* Wo  = (const float*)d_in[10];
  const float* bo  = (const float*)d_in[11];
  const float* lng = (const float*)d_in[12];
  const float* lnb = (const float*)d_in[13];
  float* out = (float*)d_out;

  char* ws = (char*)d_ws;
  u16* hb = (u16*)ws;
  u16* kb = (u16*)(ws + 26214400);
  u16* vb = (u16*)(ws + 52428800);
  u16* qb = (u16*)(ws + 78643200);
  u16* xb = kb;  // alias: consumed by embed GEMM before K written

  // weight scratch in d_out (bf16 view)
  u16* scr = (u16*)d_out;
  u16* weT = scr;                    // embed only
  u16* wqT = scr;                    // 6,553,600
  u16* wkT = scr + 6553600;          // 262,144
  u16* wvT = scr + 6815744;          // 262,144
  u16* woT = scr + 7077888;          // 262,144  (total 14.7 MB < 52.4 MB)

  // prologue: cast x; cls rows; convert We^T; embed GEMM -> hb
  cast_kernel<<<1536, 256, 0, stream>>>(x, xb, 393216);
  cls_kernel<<<512, 256, 0, stream>>>(cls, hb);
  convT_kernel<<<dim3(1, 8, 24), 256, 0, stream>>>(We, weT, 64, 512, 32768, 32768);
  gemm_plain<<<dim3(8, 4, 24), 256, 0, stream>>>(
      xb, 1536, 64, weT, 32768, be, 512, hb + 512, 12800, 512, 64);

  for (int l = 0; l < 6; ++l) {
    convT4_kernel<<<dim3(8, 8, 28), 256, 0, stream>>>(
        Wq + (long)l * 6553600, Wk + (long)l * 262144,
        Wv + (long)l * 262144, Wo + (long)l * 262144,
        wqT, wkT, wvT, woT);
    gemm_qkv<<<2400, 256, 0, stream>>>(
        hb, wqT, wkT, wvT,
        bq + (long)l * 12800, bk + (long)l * 512, bv + (long)l * 512,
        qb, kb, vb);
    attn_kernel<<<2048, 256, 0, stream>>>(qb, kb, vb);
    gemm_plain<<<dim3(200, 4, 1), 256, 0, stream>>>(
        kb, 512, 0, woT, 0, bo + (long)l * 512, 0, qb, 512, 0, 512);
    ln_kernel<<<6400, 256, 0, stream>>>(hb, qb, lng + l * 512, lnb + l * 512,
                                        (l == 5) ? out : nullptr);
  }
}

// Round 5
// 999.858 us; speedup vs baseline: 1.4132x; 1.4132x over previous
//
#include <hip/hip_runtime.h>

typedef unsigned short u16;
typedef unsigned int u32;
typedef short bf16x8 __attribute__((ext_vector_type(8)));
typedef float f32x4 __attribute__((ext_vector_type(4)));

#define AS1 __attribute__((address_space(1)))
#define AS3 __attribute__((address_space(3)))

__device__ __forceinline__ u16 f2b(float f) {
  u32 u = __float_as_uint(f);
  u += 0x7fffu + ((u >> 16) & 1u);   // round-to-nearest-even
  return (u16)(u >> 16);
}
__device__ __forceinline__ float b2f(u16 s) {
  return __uint_as_float(((u32)s) << 16);
}

__device__ __forceinline__ void gload16(const u16* g, u16* l) {
  __builtin_amdgcn_global_load_lds((const AS1 void*)g, (AS3 void*)l, 16, 0, 0);
}

// ---------------- cast x (f32) -> bf16 ----------------
__global__ __launch_bounds__(256) void cast_kernel(const float* __restrict__ x,
                                                   u16* __restrict__ xb, int n4) {
  int i = blockIdx.x * 256 + threadIdx.x;
  if (i >= n4) return;
  float4 v = ((const float4*)x)[i];
  ushort4 u;
  u.x = f2b(v.x); u.y = f2b(v.y); u.z = f2b(v.z); u.w = f2b(v.w);
  ((ushort4*)xb)[i] = u;
}

// ---------------- fill cls rows (token 0, bf16 residual) ----------------
__global__ __launch_bounds__(256) void cls_kernel(const float* __restrict__ cls,
                                                  u16* __restrict__ hb) {
  int i = blockIdx.x * 256 + threadIdx.x;  // B*128 threads, 4 elems each
  int b = i >> 7;
  int e = (i & 127) << 2;
  float4 v = *(const float4*)(cls + e);
  long off = (long)b * (25 * 512) + e;
  ushort4 u;
  u.x = f2b(v.x); u.y = f2b(v.y); u.z = f2b(v.z); u.w = f2b(v.w);
  *(ushort4*)(hb + off) = u;
}

// ---------------- transpose+convert: dst[n][k] (bf16) = src[k][n] (f32) ------
__global__ __launch_bounds__(256) void convT_kernel(const float* __restrict__ src,
                                                    u16* __restrict__ dst,
                                                    int K, int N,
                                                    long src_gstride, long dst_gstride) {
  __shared__ float t[64][65];
  const int k0 = blockIdx.x * 64, n0 = blockIdx.y * 64;
  const float* s = src + (long)blockIdx.z * src_gstride;
  u16* d = dst + (long)blockIdx.z * dst_gstride;
  for (int i = threadIdx.x; i < 4096; i += 256) {
    int r = i >> 6, c = i & 63;
    t[r][c] = s[(long)(k0 + r) * N + n0 + c];
  }
  __syncthreads();
  for (int i = threadIdx.x; i < 4096; i += 256) {
    int r = i >> 6, c = i & 63;  // r = n-local, c = k-local
    d[(long)(n0 + r) * K + k0 + c] = f2b(t[c][r]);
  }
}

// ---- fused per-layer weight convert: Wq(25 groups) + Wk + Wv + Wo, 512x512 ----
__global__ __launch_bounds__(256) void convT4_kernel(
    const float* __restrict__ wq, const float* __restrict__ wk,
    const float* __restrict__ wv, const float* __restrict__ wo,
    u16* __restrict__ dq, u16* __restrict__ dk,
    u16* __restrict__ dv, u16* __restrict__ dwo) {
  __shared__ float t[64][65];
  const int z = blockIdx.z;
  const float* src;
  u16* dst;
  if (z < 25)      { src = wq + (long)z * 262144; dst = dq + (long)z * 262144; }
  else if (z == 25){ src = wk; dst = dk; }
  else if (z == 26){ src = wv; dst = dv; }
  else             { src = wo; dst = dwo; }
  const int k0 = blockIdx.x * 64, n0 = blockIdx.y * 64;
  for (int i = threadIdx.x; i < 4096; i += 256) {
    int r = i >> 6, c = i & 63;
    t[r][c] = src[(long)(k0 + r) * 512 + n0 + c];
  }
  __syncthreads();
  for (int i = threadIdx.x; i < 4096; i += 256) {
    int r = i >> 6, c = i & 63;
    dst[(long)(n0 + r) * 512 + k0 + c] = f2b(t[c][r]);
  }
}

// ---------------- GEMM core: C = A @ Wt^T + bias ----------------
// A: bf16 [M][K] rows at a_stride; Wt: bf16 [N][K] row-major (pre-transposed).
// 128x128 tile, 4 waves, BK=64. 2-phase double-buffered (T3-min): issue next
// tile's global_load_lds into buf^1 BEFORE computing buf; one __syncthreads()
// per K-step (its vmcnt(0)+lgkmcnt(0) drain is the pipeline wait).
__device__ __forceinline__ void gemm_core(u16* lds,
    const u16* Ag, long a_stride, const u16* Wg, const float* biasg,
    u16* Cg, long c_stride, int K, int m0, int n0) {
  u16* As0 = lds;
  u16* Bs0 = lds + 8192;
  u16* As1 = lds + 16384;
  u16* Bs1 = lds + 24576;

  const int tid = threadIdx.x;
  const int lane = tid & 63;
  const int wave = tid >> 6;
  const int wr = wave >> 1, wc = wave & 1;

  // staging: wave covers 32 rows (4 instrs x 8 rows); lane -> row lane>>3,
  // chunk lane&7; LDS dest = wave-uniform base + lane*16B (HW rule).
  const int schunk = lane & 7;
  const u16* ga[4];
  const u16* gb[4];
  int lo[4];
#pragma unroll
  for (int i = 0; i < 4; ++i) {
    const int r = wave * 32 + i * 8 + (lane >> 3);
    const int csw = (schunk ^ (r & 7)) << 3;
    ga[i] = Ag + (long)(m0 + r) * a_stride + csw;
    gb[i] = Wg + (long)(n0 + r) * K + csw;
    lo[i] = (wave * 32 + i * 8) * 64;
  }

  f32x4 acc[4][4];
#pragma unroll
  for (int m = 0; m < 4; ++m)
#pragma unroll
    for (int n = 0; n < 4; ++n) {
      acc[m][n][0] = 0.f; acc[m][n][1] = 0.f;
      acc[m][n][2] = 0.f; acc[m][n][3] = 0.f;
    }

  auto STAGE = [&](int k0, u16* A, u16* B) {
#pragma unroll
    for (int i = 0; i < 4; ++i) {
      gload16(ga[i] + k0, A + lo[i]);
      gload16(gb[i] + k0, B + lo[i]);
    }
  };
  auto COMPUTE = [&](const u16* A, const u16* B) {
#pragma unroll
    for (int kk = 0; kk < 64; kk += 32) {
      const int kb = kk + ((lane >> 4) << 3);
      bf16x8 af[4], bfr[4];
#pragma unroll
      for (int m = 0; m < 4; ++m) {
        const int R = (wr << 6) + (m << 4) + (lane & 15);
        af[m] = *(const bf16x8*)&A[((R << 6) + kb) ^ ((R & 7) << 3)];
      }
#pragma unroll
      for (int n = 0; n < 4; ++n) {
        const int Cc = (wc << 6) + (n << 4) + (lane & 15);
        bfr[n] = *(const bf16x8*)&B[((Cc << 6) + kb) ^ ((Cc & 7) << 3)];
      }
#pragma unroll
      for (int m = 0; m < 4; ++m)
#pragma unroll
        for (int n = 0; n < 4; ++n)
          acc[m][n] = __builtin_amdgcn_mfma_f32_16x16x32_bf16(af[m], bfr[n],
                                                              acc[m][n], 0, 0, 0);
    }
  };

  const int nt = K >> 6;
  STAGE(0, As0, Bs0);
  __syncthreads();                       // tile 0 resident (vmcnt0 drain)
  for (int t = 0; t < nt; ++t) {
    u16* cA = (t & 1) ? As1 : As0;
    u16* cB = (t & 1) ? Bs1 : Bs0;
    if (t + 1 < nt) {
      u16* nA = (t & 1) ? As0 : As1;
      u16* nB = (t & 1) ? Bs0 : Bs1;
      STAGE((t + 1) << 6, nA, nB);       // in flight during compute
    }
    COMPUTE(cA, cB);
    if (t + 1 < nt) __syncthreads();     // drains next tile's loads + WAR fence
  }

  // epilogue: C/D layout col=lane&15, row=(lane>>4)*4+j (HW-verified)
  const int lcol = lane & 15;
  const int lrow = (lane >> 4) << 2;
#pragma unroll
  for (int n = 0; n < 4; ++n) {
    const int col = n0 + (wc << 6) + (n << 4) + lcol;
    const float bv = biasg[col];
#pragma unroll
    for (int m = 0; m < 4; ++m) {
      const int row = m0 + (wr << 6) + (m << 4) + lrow;
#pragma unroll
      for (int j = 0; j < 4; ++j) {
        const float val = acc[m][n][j] + bv;
        Cg[(long)(row + j) * c_stride + col] = f2b(val);
      }
    }
  }
}

// plain grouped wrapper: grid (mtiles, ntiles, groups), XCD-swizzled.
// All launch grids have total % 8 == 0 (768, 800) -> simple swizzle bijective.
__global__ __launch_bounds__(256) void gemm_plain(
    const u16* __restrict__ Abase, long a_stride, long a_goff,
    const u16* __restrict__ Wbase, long w_gstride,
    const float* __restrict__ biasbase, long bias_gstride,
    u16* __restrict__ Cb, long c_stride, long c_goff, int K) {
  __shared__ u16 lds[4 * 8192];
  const int gx = gridDim.x, gy = gridDim.y;
  int lin = blockIdx.x + gx * (blockIdx.y + gy * blockIdx.z);
  const int total = gx * gy * gridDim.z;
  const int chunk = total >> 3;
  lin = (lin & 7) * chunk + (lin >> 3);   // XCD-contiguous work chunks
  const int g = lin / (gx * gy);
  const int rem = lin % (gx * gy);
  const int mt = rem % gx;
  const int nt = rem / gx;
  gemm_core(lds,
            Abase + (long)g * a_goff, a_stride,
            Wbase + (long)g * w_gstride,
            biasbase + (long)g * bias_gstride,
            Cb + (long)g * c_goff, c_stride, K,
            mt * 128, nt * 128);
}

// fused Q(25 groups)+K+V: 1D grid of 2400 blocks, XCD-swizzled (2400 = 8*300)
__global__ __launch_bounds__(256) void gemm_qkv(
    const u16* __restrict__ hb,
    const u16* __restrict__ wqT, const u16* __restrict__ wkT, const u16* __restrict__ wvT,
    const float* __restrict__ bq, const float* __restrict__ bk, const float* __restrict__ bv,
    u16* __restrict__ qb, u16* __restrict__ kb, u16* __restrict__ vb) {
  __shared__ u16 lds[4 * 8192];
  const int bid = (blockIdx.x & 7) * 300 + (blockIdx.x >> 3);
  const u16* Ag; long a_str; const u16* Wg; const float* bg; u16* Cg; long c_str;
  int mt, nt;
  if (bid < 800) {           // Q: per-joint groups
    const int g = bid >> 5, rem = bid & 31;
    mt = rem >> 2; nt = rem & 3;
    Ag = hb + (long)g * 512; a_str = 12800;
    Wg = wqT + (long)g * 262144; bg = bq + (long)g * 512;
    Cg = qb + (long)g * 512; c_str = 12800;
  } else if (bid < 1600) {   // K
    const int rem = bid - 800;
    mt = rem >> 2; nt = rem & 3;
    Ag = hb; a_str = 512; Wg = wkT; bg = bk; Cg = kb; c_str = 512;
  } else {                   // V
    const int rem = bid - 1600;
    mt = rem >> 2; nt = rem & 3;
    Ag = hb; a_str = 512; Wg = wvT; bg = bv; Cg = vb; c_str = 512;
  }
  gemm_core(lds, Ag, a_str, Wg, bg, Cg, c_str, 512, mt * 128, nt * 128);
}

// ---------------- attention: wave per (batch, head) ----------------
// NO min-waves bound: round-4's (256,4) forced VGPR=64 -> scratch spills
// (WRITE_SIZE 237 MB vs 26 MB true) and +50 us/dispatch. Natural allocation
// (~100 VGPR) is spill-free.
__global__ __launch_bounds__(256) void attn_kernel(const u16* __restrict__ q,
                                                   u16* __restrict__ kio,
                                                   const u16* __restrict__ v) {
  __shared__ u16 ks_[25 * 256];
  __shared__ u16 vs_[25 * 256];
  const int tid = threadIdx.x;
  const int b = blockIdx.x >> 1;
  const int h0 = blockIdx.x & 1;      // head-group (4 heads)
  const long base = (long)b * 25 * 512;

  for (int i = tid; i < 800; i += 256) {
    const int j = i >> 5, c = i & 31;
    const long goff = base + (long)j * 512 + h0 * 256 + c * 8;
    ((uint4*)ks_)[i] = *(const uint4*)(kio + goff);
    ((uint4*)vs_)[i] = *(const uint4*)(v + goff);
  }
  __syncthreads();

  const int w = tid >> 6;
  const int lane = tid & 63;
  const int qi = lane >> 1;
  const int half = lane & 1;
  if (qi < 25) {
    const int h = h0 * 4 + w;
    const int dslice = w * 64 + half * 32;

    const u16* qrow = q + base + (long)qi * 512 + h * 64 + half * 32;
    float buf[32];
#pragma unroll
    for (int c = 0; c < 4; ++c) {
      uint4 t = *(const uint4*)(qrow + c * 8);
      const u32 tt[4] = {t.x, t.y, t.z, t.w};
#pragma unroll
      for (int e = 0; e < 4; ++e) {
        buf[c * 8 + 2 * e]     = b2f((u16)tt[e]);
        buf[c * 8 + 2 * e + 1] = b2f((u16)(tt[e] >> 16));
      }
    }

    float sc[25];
    float mx = -1e30f;
#pragma unroll
    for (int j = 0; j < 25; ++j) {
      float s = 0.f;
      const u16* kr = &ks_[j * 256 + dslice];
#pragma unroll
      for (int d = 0; d < 32; d += 2) {
        u32 t = *(const u32*)(kr + d);
        s += buf[d] * b2f((u16)t) + buf[d + 1] * b2f((u16)(t >> 16));
      }
      s += __shfl_xor(s, 1);
      s *= 0.125f;
      sc[j] = s;
      mx = fmaxf(mx, s);
    }
    float sum = 0.f;
#pragma unroll
    for (int j = 0; j < 25; ++j) {
      sc[j] = __expf(sc[j] - mx);
      sum += sc[j];
    }
    const float inv = 1.f / sum;

#pragma unroll
    for (int d = 0; d < 32; ++d) buf[d] = 0.f;
#pragma unroll
    for (int j = 0; j < 25; ++j) {
      const float wj = sc[j];
      const u16* vr = &vs_[j * 256 + dslice];
#pragma unroll
      for (int d = 0; d < 32; d += 2) {
        u32 t = *(const u32*)(vr + d);
        buf[d]     += wj * b2f((u16)t);
        buf[d + 1] += wj * b2f((u16)(t >> 16));
      }
    }

    u16* orow = kio + base + (long)qi * 512 + h * 64 + half * 32;
#pragma unroll
    for (int c = 0; c < 4; ++c) {
      uint4 t;
      u32 tt[4];
#pragma unroll
      for (int e = 0; e < 4; ++e)
        tt[e] = (u32)f2b(buf[c * 8 + 2 * e] * inv) |
                ((u32)f2b(buf[c * 8 + 2 * e + 1] * inv) << 16);
      t.x = tt[0]; t.y = tt[1]; t.z = tt[2]; t.w = tt[3];
      *(uint4*)(orow + c * 8) = t;
    }
  }
}

// ---------------- residual + LayerNorm (bf16 residual) ----------------
__global__ __launch_bounds__(256) void ln_kernel(u16* hb,
                                                 const u16* __restrict__ o,
                                                 const float* __restrict__ g,
                                                 const float* __restrict__ bta,
                                                 float* fout) {
  const int lane = threadIdx.x & 63;
  const int wave = threadIdx.x >> 6;
  const long row = (long)blockIdx.x * 4 + wave;
  u16* hr = hb + row * 512;
  const u16* orow = o + row * 512;
  const int base = lane << 3;
  uint4 hv4 = *(const uint4*)(hr + base);
  uint4 ov = *(const uint4*)(orow + base);
  const u32 ha[4] = {hv4.x, hv4.y, hv4.z, hv4.w};
  const u32 oa[4] = {ov.x, ov.y, ov.z, ov.w};
  float y[8];
#pragma unroll
  for (int e = 0; e < 4; ++e) {
    y[2 * e]     = b2f((u16)ha[e])         + b2f((u16)oa[e]);
    y[2 * e + 1] = b2f((u16)(ha[e] >> 16)) + b2f((u16)(oa[e] >> 16));
  }
  float s = 0.f, ss = 0.f;
#pragma unroll
  for (int i = 0; i < 8; ++i) { s += y[i]; ss += y[i] * y[i]; }
#pragma unroll
  for (int off = 32; off > 0; off >>= 1) {
    s += __shfl_down(s, off);
    ss += __shfl_down(ss, off);
  }
  s = __shfl(s, 0);
  ss = __shfl(ss, 0);
  const float mean = s * (1.f / 512.f);
  const float var = ss * (1.f / 512.f) - mean * mean;
  const float rinv = rsqrtf(var + 1e-5f);
  float4 g0 = *(const float4*)(g + base);
  float4 g1 = *(const float4*)(g + base + 4);
  float4 b0 = *(const float4*)(bta + base);
  float4 b1 = *(const float4*)(bta + base + 4);
  float r[8];
  r[0] = (y[0] - mean) * rinv * g0.x + b0.x;
  r[1] = (y[1] - mean) * rinv * g0.y + b0.y;
  r[2] = (y[2] - mean) * rinv * g0.z + b0.z;
  r[3] = (y[3] - mean) * rinv * g0.w + b0.w;
  r[4] = (y[4] - mean) * rinv * g1.x + b1.x;
  r[5] = (y[5] - mean) * rinv * g1.y + b1.y;
  r[6] = (y[6] - mean) * rinv * g1.z + b1.z;
  r[7] = (y[7] - mean) * rinv * g1.w + b1.w;
  uint4 hv;
  hv.x = (u32)f2b(r[0]) | ((u32)f2b(r[1]) << 16);
  hv.y = (u32)f2b(r[2]) | ((u32)f2b(r[3]) << 16);
  hv.z = (u32)f2b(r[4]) | ((u32)f2b(r[5]) << 16);
  hv.w = (u32)f2b(r[6]) | ((u32)f2b(r[7]) << 16);
  *(uint4*)(hr + base) = hv;
  if (fout) {
    float* fr = fout + row * 512 + base;
    float4 w0 = {r[0], r[1], r[2], r[3]};
    float4 w1 = {r[4], r[5], r[6], r[7]};
    *(float4*)(fr) = w0;
    *(float4*)(fr + 4) = w1;
  }
}

// ---------------- host launcher ----------------
// d_in: x, We, be, cls, Wk, bk, Wv, bv, Wq, bq, Wo, bo, ln_g, ln_b
// ws (100 MiB): hb@0, kb@25M(=xb alias), vb@50M, qb@75M
// d_out doubles as bf16 weight scratch during layers; final LN rewrites it.
extern "C" void kernel_launch(void* const* d_in, const int* in_sizes, int n_in,
                              void* d_out, int out_size, void* d_ws, size_t ws_size,
                              hipStream_t stream) {
  const float* x   = (const float*)d_in[0];
  const float* We  = (const float*)d_in[1];
  const float* be  = (const float*)d_in[2];
  const float* cls = (const float*)d_in[3];
  const float* Wk  = (const float*)d_in[4];
  const float* bk  = (const float*)d_in[5];
  const float* Wv  = (const float*)d_in[6];
  const float* bv  = (const float*)d_in[7];
  const float* Wq  = (const float*)d_in[8];
  const float* bq  = (const float*)d_in[9];
  const float* Wo  = (const float*)d_in[10];
  const float* bo  = (const float*)d_in[11];
  const float* lng = (const float*)d_in[12];
  const float* lnb = (const float*)d_in[13];
  float* out = (float*)d_out;

  char* ws = (char*)d_ws;
  u16* hb = (u16*)ws;
  u16* kb = (u16*)(ws + 26214400);
  u16* vb = (u16*)(ws + 52428800);
  u16* qb = (u16*)(ws + 78643200);
  u16* xb = kb;  // alias: consumed by embed GEMM before K written

  // weight scratch in d_out (bf16 view)
  u16* scr = (u16*)d_out;
  u16* weT = scr;                    // embed only
  u16* wqT = scr;                    // 6,553,600
  u16* wkT = scr + 6553600;          // 262,144
  u16* wvT = scr + 6815744;          // 262,144
  u16* woT = scr + 7077888;          // 262,144  (total 14.7 MB < 52.4 MB)

  // prologue: cast x; cls rows; convert We^T; embed GEMM -> hb
  cast_kernel<<<1536, 256, 0, stream>>>(x, xb, 393216);
  cls_kernel<<<512, 256, 0, stream>>>(cls, hb);
  convT_kernel<<<dim3(1, 8, 24), 256, 0, stream>>>(We, weT, 64, 512, 32768, 32768);
  gemm_plain<<<dim3(8, 4, 24), 256, 0, stream>>>(
      xb, 1536, 64, weT, 32768, be, 512, hb + 512, 12800, 512, 64);

  for (int l = 0; l < 6; ++l) {
    convT4_kernel<<<dim3(8, 8, 28), 256, 0, stream>>>(
        Wq + (long)l * 6553600, Wk + (long)l * 262144,
        Wv + (long)l * 262144, Wo + (long)l * 262144,
        wqT, wkT, wvT, woT);
    gemm_qkv<<<2400, 256, 0, stream>>>(
        hb, wqT, wkT, wvT,
        bq + (long)l * 12800, bk + (long)l * 512, bv + (long)l * 512,
        qb, kb, vb);
    attn_kernel<<<2048, 256, 0, stream>>>(qb, kb, vb);
    gemm_plain<<<dim3(200, 4, 1), 256, 0, stream>>>(
        kb, 512, 0, woT, 0, bo + (long)l * 512, 0, qb, 512, 0, 512);
    ln_kernel<<<6400, 256, 0, stream>>>(hb, qb, lng + l * 512, lnb + l * 512,
                                        (l == 5) ? out : nullptr);
  }
}